// Round 5
// baseline (253.499 us; speedup 1.0000x reference)
//
#include <hip/hip_runtime.h>

#define M 4096
#define L 32
#define K 64
#define NBLK 64
#define BLOCK 1024
#define NPW 4                    // nodes per wave
#define MK (M * K)
#define FLAG_BASE 0xAAAAAAAAu    // ws poison pattern; flag value = BASE + round

// Persistent kernel, flag-vector global barrier (R5).
// 64 blocks x 1024 threads; wave w of block b owns nodes base..base+3,
// base = 64*b + 4*w; lane k owns in-edge k of each node.
//
// Publish protocol (single-wave causality chain):
//  - lanes<4 stash vals in LDS sres[64]; __syncthreads
//  - wave 0 publishes the block's contiguous 64-float gbuf segment with ONE
//    64-lane agent-scope atomicExch (RMW executes at the coherence point;
//    returned value + asm use forces the vmcnt wait)
//  - wave 0 lane 0 then stores flag[blk] = FLAG_BASE + round (absolute,
//    poison-proof -> no memset dispatch needed)
//  - flag visible  =>  segment already readable at L3. No cross-wave
//    store-ordering assumptions, no fences, no buffer_inv.
// Wait: wave 0 reads all 64 flags in one coalesced sc1 load, ballot-checks.
__global__ __launch_bounds__(BLOCK, 4)
void net_kernel(const float* __restrict__ x,
                const float* __restrict__ w_in,
                const float* __restrict__ b_in,
                const float* __restrict__ w,
                const float* __restrict__ b,
                const int* __restrict__ igraf,
                float* __restrict__ out,
                unsigned* __restrict__ flags,
                float* __restrict__ gbuf)
{
    __shared__ float sv[M];       // full previous-layer value vector (16 KB)
    __shared__ float sres[64];    // this block's 64 freshly computed values

    const int tid  = threadIdx.x;
    const int blk  = blockIdx.x;
    const int wave = tid >> 6;
    const int lane = tid & 63;
    const int base = blk * (16 * NPW) + wave * NPW;  // first node of this wave
    const bool lastblk = (blk == NBLK - 1);          // owns node M-1

    // Layer-0 fragment prefetch (4 nodes/wave; bias on lanes 0-3).
    float wv[NPW]; int iv[NPW]; float breg = 0.0f;
    {
        const size_t b0 = (size_t)base * K + (size_t)lane;
        #pragma unroll
        for (int j = 0; j < NPW; ++j) {
            wv[j] = w[b0 + (size_t)j * K];
            iv[j] = igraf[b0 + (size_t)j * K];
        }
        if (lane < NPW) breg = b[base + lane];
    }

    // v0 = relu(w_in * x + b_in), redundant per block, into LDS.
    {
        const float4 x4 = ((const float4*)x)[tid];
        const float4 wi = ((const float4*)w_in)[tid];
        const float4 bi = ((const float4*)b_in)[tid];
        float4 r;
        r.x = fmaxf(fmaf(wi.x, x4.x, bi.x), 0.0f);
        r.y = fmaxf(fmaf(wi.y, x4.y, bi.y), 0.0f);
        r.z = fmaxf(fmaf(wi.z, x4.z, bi.z), 0.0f);
        r.w = fmaxf(fmaf(wi.w, x4.w, bi.w), 0.0f);
        ((float4*)sv)[tid] = r;
    }
    __syncthreads();

    for (int l = 0; l < L; ++l) {
        // Gather + product for 4 independent nodes (ILP overlaps the chains).
        float p[NPW];
        #pragma unroll
        for (int j = 0; j < NPW; ++j) p[j] = wv[j] * sv[iv[j]];

        // 4 independent 64-lane butterfly reductions.
        #pragma unroll
        for (int j = 0; j < NPW; ++j) {
            #pragma unroll
            for (int off = 32; off > 0; off >>= 1)
                p[j] += __shfl_xor(p[j], off, 64);
        }

        // Lane j (j<4) finishes node base+j.
        float pj = p[0];
        pj = (lane == 1) ? p[1] : pj;
        pj = (lane == 2) ? p[2] : pj;
        pj = (lane == 3) ? p[3] : pj;
        const float val = 1.0f / (1.0f + __expf(-(pj + breg)));

        if (l == L - 1) {
            // Unique writer: lane<4 AND base+lane==M-1 -> wave 15, lane 3.
            if (lastblk && (lane < NPW) && (base + lane == M - 1)) out[0] = val;
            break;
        }

        // Stash this block's 64 values in LDS for the single-wave publish.
        if (lane < NPW) sres[wave * NPW + lane] = val;
        __syncthreads();

        // Prefetch next layer's fragments; drain overlaps the poll window.
        if ((l + 2 < L) || lastblk) {
            const size_t nb = (size_t)(l + 1) * MK + (size_t)base * K + (size_t)lane;
            #pragma unroll
            for (int j = 0; j < NPW; ++j) {
                wv[j] = w[nb + (size_t)j * K];
                iv[j] = igraf[nb + (size_t)j * K];
            }
            if (lane < NPW) breg = b[(l + 1) * M + base + lane];
        }

        if (wave == 0) {
            // One 64-lane agent-scope exchange publishes the whole segment.
            // RMW executes at the coherence point; asm use of the returned
            // value forces the vmcnt wait BEFORE the flag store below.
            float old = __hip_atomic_exchange(
                &gbuf[((l + 1) & 1) * M + blk * 64 + lane], sres[lane],
                __ATOMIC_RELAXED, __HIP_MEMORY_SCOPE_AGENT);
            __asm__ volatile("" :: "v"(old));
            if (lane == 0)
                __hip_atomic_store(&flags[blk], FLAG_BASE + (unsigned)(l + 1),
                                   __ATOMIC_RELAXED, __HIP_MEMORY_SCOPE_AGENT);
        }

        if ((l == L - 2) && !lastblk) return;  // only block 63 runs layer 31

        // Wait: all 64 flags in one coalesced load, ballot-check.
        if (wave == 0) {
            const unsigned tgt = FLAG_BASE + (unsigned)(l + 1);
            for (;;) {
                const unsigned f = __hip_atomic_load(
                    &flags[lane], __ATOMIC_RELAXED, __HIP_MEMORY_SCOPE_AGENT);
                if (__ballot(f >= tgt) == ~0ull) break;
                __builtin_amdgcn_s_sleep(1);
            }
        }
        __syncthreads();

        // Re-stage new v into LDS (sc1 loads: gbuf never cached in L1/L2).
        {
            const float* src = gbuf + ((l + 1) & 1) * M;
            #pragma unroll
            for (int j = 0; j < 4; ++j) {
                const int idx = tid + j * BLOCK;
                sv[idx] = __hip_atomic_load(&src[idx], __ATOMIC_RELAXED,
                                            __HIP_MEMORY_SCOPE_AGENT);
            }
        }
        __syncthreads();
    }
}

extern "C" void kernel_launch(void* const* d_in, const int* in_sizes, int n_in,
                              void* d_out, int out_size, void* d_ws, size_t ws_size,
                              hipStream_t stream) {
    const float* x     = (const float*)d_in[0];
    const float* w_in  = (const float*)d_in[1];
    const float* b_in  = (const float*)d_in[2];
    const float* b     = (const float*)d_in[4];
    const float* wt    = (const float*)d_in[3];
    const int*   igraf = (const int*)d_in[5];
    float*       out   = (float*)d_out;

    unsigned* flags = (unsigned*)d_ws;                 // 64 x u32, poison-proof
    float*    gbuf  = (float*)((char*)d_ws + 16384);   // 2 x M floats exchange

    // No memset: flags use absolute values biased by the 0xAA poison pattern.
    hipLaunchKernelGGL(net_kernel, dim3(NBLK), dim3(BLOCK), 0, stream,
                       x, w_in, b_in, wt, b, igraf, out, flags, gbuf);
    (void)in_sizes; (void)n_in; (void)out_size; (void)ws_size;
}